// Round 3
// baseline (5476.320 us; speedup 1.0000x reference)
//
#include <hip/hip_runtime.h>
#include <hip/hip_bf16.h>
#include <cfloat>

using bf16 = __hip_bfloat16;

constexpr int Bb = 8, Nn = 4096, Kk = 20;
constexpr int BN = Bb * Nn;                     // 32768
constexpr int Mrows = BN * Kk;                  // 655360
constexpr float EPSf = 1e-5f;

static __device__ __forceinline__ float b2f(bf16 v){ return __bfloat162float(v); }
static __device__ __forceinline__ bf16 f2b(float v){ return __float2bfloat16(v); }
static __device__ __forceinline__ unsigned short f2bu(float v){
  union { bf16 b; unsigned short u; } cv; cv.b = __float2bfloat16(v); return cv.u;
}
static __device__ __forceinline__ float ldf(bf16 v){ return b2f(v); }
static __device__ __forceinline__ float ldf(float v){ return v; }

// ---------------- zero workspace region ----------------
__global__ void zero_kernel(float* __restrict__ p, int n){
  int i = blockIdx.x*256 + threadIdx.x;
  if (i < n) p[i] = 0.f;
}

// ---------------- KNN phase A: per-point top-20 over a j-stripe ----------------
// grid: b(8) x chunk(16) x stripe(2) = 256 blocks of 256 threads.
// Replicates reference fp32 arithmetic order exactly (contract off).
__global__ __launch_bounds__(256) void knnA_kernel(const float* __restrict__ x,
                                                   float* __restrict__ pv, int* __restrict__ pi){
#pragma clang fp contract(off)
  __shared__ float4 p4[2048];
  int blk = blockIdx.x;
  int stripe = blk & 1;
  int chunk  = (blk >> 1) & 15;
  int b      = blk >> 5;
  const float* xb = x + b*3*Nn;
  int j0 = stripe*2048;
  for (int u = threadIdx.x; u < 2048; u += 256){
    int j = j0 + u;
    float a0 = xb[j];
    float a1 = xb[Nn + j];
    float a2 = xb[2*Nn + j];
    float s = a0*a0; s = s + a1*a1; s = s + a2*a2;   // xx = ((x^2)+(y^2))+(z^2)
    p4[u] = make_float4(a0, a1, a2, s);
  }
  __syncthreads();
  int i = chunk*256 + threadIdx.x;
  float xi = xb[i], yi = xb[Nn+i], zi = xb[2*Nn+i];
  float ni = xi*xi; ni = ni + yi*yi; ni = ni + zi*zi;
  float mni = -ni;
  float tv[Kk]; int ti[Kk];
  #pragma unroll
  for (int s=0;s<Kk;++s){ tv[s] = -FLT_MAX; ti[s] = 0; }
  for (int u=0; u<2048; ++u){
    float4 p = p4[u];
    float dot = xi*p.x; dot = dot + yi*p.y; dot = dot + zi*p.z;
    float inner = -2.0f*dot;
    float nd = mni - inner; nd = nd - p.w;            // (-xx_i - inner) - xx_j
    if (nd > tv[Kk-1]){
      #pragma unroll
      for (int s=Kk-1; s>=1; --s){
        bool cs = nd > tv[s];
        bool cp = nd > tv[s-1];
        tv[s] = cs ? (cp ? tv[s-1] : nd) : tv[s];
        ti[s] = cs ? (cp ? ti[s-1] : (j0+u)) : ti[s];
      }
      if (nd > tv[0]){ tv[0] = nd; ti[0] = j0+u; }
    }
  }
  long long base = ((long long)(b*Nn + i)*2 + stripe)*Kk;
  #pragma unroll
  for (int s=0;s<Kk;++s){ pv[base+s] = tv[s]; pi[base+s] = ti[s]; }
}

// ---------------- KNN phase B: merge the two stripe lists ----------------
__global__ __launch_bounds__(256) void knnB_kernel(const float* __restrict__ pv,
                                                   const int* __restrict__ pi,
                                                   int* __restrict__ idx){
  int p = blockIdx.x*256 + threadIdx.x;
  if (p >= BN) return;
  long long base = (long long)p*2*Kk;
  float av[Kk]; int ai[Kk];
  #pragma unroll
  for (int s=0;s<Kk;++s){ av[s]=pv[base+s]; ai[s]=pi[base+s]; }
  for (int t=0;t<Kk;++t){
    float nd = pv[base+Kk+t]; int j = pi[base+Kk+t];
    if (nd > av[Kk-1]){
      #pragma unroll
      for (int s=Kk-1;s>=1;--s){
        bool cs = nd > av[s];
        bool cp = nd > av[s-1];
        av[s] = cs ? (cp?av[s-1]:nd) : av[s];
        ai[s] = cs ? (cp?ai[s-1]:j) : ai[s];
      }
      if (nd > av[0]){ av[0]=nd; ai[0]=j; }
    }
  }
  #pragma unroll
  for (int s=0;s<Kk;++s) idx[(long long)p*Kk+s] = ai[s];
}

// ---------------- layer-1 feature stats: sum(f) and f^T f (6x6) ----------------
__global__ __launch_bounds__(256) void gramf_kernel(const float* __restrict__ x,
                                                    const int* __restrict__ idx,
                                                    float* __restrict__ part){
  float acc[36]; float s6[6];
  #pragma unroll
  for (int a=0;a<36;++a) acc[a]=0.f;
  #pragma unroll
  for (int a=0;a<6;++a) s6[a]=0.f;
  for (long long row = blockIdx.x*256 + threadIdx.x; row < Mrows; row += (long long)gridDim.x*256){
    int bn = (int)(row / Kk);
    int b = bn >> 12, n = bn & 4095;
    int j = idx[row];
    const float* xb = x + b*3*Nn;
    float f[6];
    f[0]=xb[j];  f[1]=xb[Nn+j];  f[2]=xb[2*Nn+j];
    f[3]=xb[n];  f[4]=xb[Nn+n];  f[5]=xb[2*Nn+n];
    #pragma unroll
    for (int a=0;a<6;++a){
      s6[a] += f[a];
      #pragma unroll
      for (int c=0;c<6;++c) acc[a*6+c] = fmaf(f[a], f[c], acc[a*6+c]);
    }
  }
  __shared__ float red[256];
  for (int v=0; v<42; ++v){
    red[threadIdx.x] = (v<36)? acc[v] : s6[v-36];
    __syncthreads();
    for (int s=128; s>0; s>>=1){
      if (threadIdx.x < s) red[threadIdx.x] += red[threadIdx.x+s];
      __syncthreads();
    }
    if (threadIdx.x==0) part[blockIdx.x*48 + v] = red[0];
    __syncthreads();
  }
}

__global__ void reducef_kernel(const float* __restrict__ part, float* __restrict__ Gf,
                               float* __restrict__ sumf){
  int t = threadIdx.x;
  if (t < 42){
    float s = 0.f;
    for (int i=0;i<256;++i) s += part[i*48 + t];
    if (t<36) Gf[t]=s; else sumf[t-36]=s;
  }
}

// ---------------- Gram: G = H^T H, 64x64 tiles ----------------
template<int CIN, typename T>
__global__ __launch_bounds__(256) void gram_kernel(const T* __restrict__ H, int M,
                                                   float* __restrict__ G){
  constexpr int Tt = CIN/64;
  int tile = blockIdx.x % (Tt*Tt);
  int chunk = blockIdx.x / (Tt*Tt);
  int nchunks = gridDim.x / (Tt*Tt);
  int tr = tile / Tt, tc = tile % Tt;
  __shared__ float Aw[16][64];
  __shared__ float Bw[16][64];
  int rpc = (M + nchunks - 1)/nchunks;
  int r0 = chunk*rpc; int r1 = min(M, r0+rpc);
  int tx = threadIdx.x & 15, ty = threadIdx.x >> 4;
  float acc[4][4] = {};
  for (int rb=r0; rb<r1; rb+=16){
    int nr = min(16, r1-rb);
    for (int u=threadIdx.x; u<1024; u+=256){
      int rr = u >> 6, cc = u & 63;
      float av=0.f, bv=0.f;
      if (rr < nr){
        const T* hp = H + (size_t)(rb+rr)*CIN;
        av = ldf(hp[tr*64+cc]);
        bv = ldf(hp[tc*64+cc]);
      }
      Aw[rr][cc]=av; Bw[rr][cc]=bv;
    }
    __syncthreads();
    for (int r=0;r<nr;++r){
      float a[4], bq[4];
      #pragma unroll
      for (int u=0;u<4;++u){ a[u]=Aw[r][ty*4+u]; bq[u]=Bw[r][tx*4+u]; }
      #pragma unroll
      for (int u=0;u<4;++u)
        #pragma unroll
        for (int v=0;v<4;++v) acc[u][v] = fmaf(a[u], bq[v], acc[u][v]);
    }
    __syncthreads();
  }
  #pragma unroll
  for (int u=0;u<4;++u)
    #pragma unroll
    for (int v=0;v<4;++v)
      atomicAdd(&G[(size_t)(tr*64+ty*4+u)*CIN + (tc*64+tx*4+v)], acc[u][v]);
}

// ---------------- column sums of H ----------------
template<int CIN, typename T>
__global__ __launch_bounds__(256) void colsum_kernel(const T* __restrict__ H, int M,
                                                     float* __restrict__ sumh){
  int rpb = (M + gridDim.x - 1)/gridDim.x;
  int r0 = blockIdx.x*rpb, r1 = min(M, r0+rpb);
  if constexpr (CIN <= 256){
    constexpr int RP = 256/CIN;
    int c = threadIdx.x % CIN;
    int sub = threadIdx.x / CIN;
    float a = 0.f;
    for (int r=r0+sub; r<r1; r+=RP) a += ldf(H[(size_t)r*CIN + c]);
    atomicAdd(&sumh[c], a);
  } else {
    float a0=0.f, a1=0.f;
    for (int r=r0;r<r1;++r){
      a0 += ldf(H[(size_t)r*CIN + threadIdx.x]);
      a1 += ldf(H[(size_t)r*CIN + threadIdx.x + 256]);
    }
    atomicAdd(&sumh[threadIdx.x], a0);
    atomicAdd(&sumh[threadIdx.x+256], a1);
  }
}

// ---------------- P = G @ W ----------------
__global__ void kP_kernel(const float* __restrict__ G, const float* __restrict__ Wf,
                          float* __restrict__ P, int Cin, int Cout){
  int id = blockIdx.x*256 + threadIdx.x;
  if (id >= Cin*Cout) return;
  int i = id / Cout, j = id - i*Cout;
  float s = 0.f;
  for (int k=0;k<Cin;++k) s = fmaf(G[(size_t)i*Cin+k], Wf[(size_t)k*Cout+j], s);
  P[id] = s;
}

// ---------------- scale/shift from Gram-derived BN stats ----------------
__global__ void kFinal_kernel(const float* __restrict__ P, const float* __restrict__ sumh,
                              const float* __restrict__ Wf, const float* __restrict__ g,
                              const float* __restrict__ bb, float* __restrict__ scale,
                              float* __restrict__ shift, int Cin, int Cout, float invM){
  int j = blockIdx.x*256 + threadIdx.x;
  if (j >= Cout) return;
  float mean=0.f, e2=0.f;
  for (int i=0;i<Cin;++i){
    float w = Wf[(size_t)i*Cout + j];
    mean = fmaf(sumh[i], w, mean);
    e2   = fmaf(w, P[(size_t)i*Cout + j], e2);
  }
  mean *= invM; e2 *= invM;
  float var = e2 - mean*mean;
  float inv = rsqrtf(var + EPSf);
  float sc = g[j]*inv;
  scale[j]=sc;
  shift[j]=bb[j] - mean*sc;
}

// ---------------- layer-2 stats: on-the-fly H1 -> Gram2(64x64) + colsum2 ----------------
__global__ __launch_bounds__(256) void stats2_kernel(const float* __restrict__ x,
    const int* __restrict__ idx, const float* __restrict__ W1f,
    const float* __restrict__ sc1v, const float* __restrict__ sh1v,
    float* __restrict__ G2, float* __restrict__ sum2){
  __shared__ float W1s[6][64];
  __shared__ float fsh[16][6];
  __shared__ float Aw[16][64];
  __shared__ float scs[64], shs[64];
  int tid = threadIdx.x;
  for (int u=tid; u<384; u+=256) W1s[u/64][u%64] = W1f[u];
  if (tid < 64){ scs[tid]=sc1v[tid]; shs[tid]=sh1v[tid]; }
  __syncthreads();
  int rpc = (Mrows + gridDim.x - 1)/gridDim.x;
  int r0 = blockIdx.x*rpc, r1 = min(Mrows, r0+rpc);
  int ty = tid >> 4, tx = tid & 15;
  int myc = tid & 63;
  float acc[4][4] = {};
  float cs = 0.f;
  for (int rb=r0; rb<r1; rb+=16){
    if (tid < 16){
      int row = rb + tid;
      float f0=0,f1=0,f2=0,f3=0,f4=0,f5=0;
      if (row < r1){
        int bn = row / Kk;
        int b = bn >> 12, n = bn & 4095;
        int j = idx[row];
        const float* xb = x + b*3*Nn;
        f0=xb[j]; f1=xb[Nn+j]; f2=xb[2*Nn+j];
        f3=xb[n]; f4=xb[Nn+n]; f5=xb[2*Nn+n];
      }
      fsh[tid][0]=f0; fsh[tid][1]=f1; fsh[tid][2]=f2;
      fsh[tid][3]=f3; fsh[tid][4]=f4; fsh[tid][5]=f5;
    }
    __syncthreads();
    #pragma unroll
    for (int k=0;k<4;++k){
      int rr = (tid>>6) + k*4;
      float y = 0.f;
      #pragma unroll
      for (int i=0;i<6;++i) y = fmaf(fsh[rr][i], W1s[i][myc], y);
      float v = fmaxf(fmaf(y, scs[myc], shs[myc]), 0.f);
      if (rb + rr >= r1) v = 0.f;
      Aw[rr][myc] = v;
      cs += v;
    }
    __syncthreads();
    for (int r=0;r<16;++r){
      float a[4], bq[4];
      #pragma unroll
      for (int u=0;u<4;++u){ a[u]=Aw[r][ty*4+u]; bq[u]=Aw[r][tx*4+u]; }
      #pragma unroll
      for (int u=0;u<4;++u)
        #pragma unroll
        for (int v=0;v<4;++v) acc[u][v]=fmaf(a[u],bq[v],acc[u][v]);
    }
    __syncthreads();
  }
  #pragma unroll
  for (int u=0;u<4;++u)
    #pragma unroll
    for (int v=0;v<4;++v)
      atomicAdd(&G2[(size_t)(ty*4+u)*64 + tx*4+v], acc[u][v]);
  atomicAdd(&sum2[myc], cs);
}

// ---------------- fused layers 1+2: gather->H1->x1, H1@W2 -> H2(bf16) + x2 ----------------
__global__ __launch_bounds__(64) void fl12_kernel(const float* __restrict__ x,
    const int* __restrict__ idx, const float* __restrict__ W1f,
    const float* __restrict__ sc1v, const float* __restrict__ sh1v,
    const float* __restrict__ W2f, const float* __restrict__ sc2v,
    const float* __restrict__ sh2v, bf16* __restrict__ H2, bf16* __restrict__ cat){
  __shared__ float fsh[Kk][6];
  __shared__ float h1[Kk][64];
  __shared__ float mm[4][64];
  int bn = blockIdx.x, b = bn>>12, n = bn & 4095;
  int tid = threadIdx.x;
  if (tid < Kk){
    int j = idx[(size_t)bn*Kk + tid];
    const float* xb = x + b*3*Nn;
    fsh[tid][0]=xb[j]; fsh[tid][1]=xb[Nn+j]; fsh[tid][2]=xb[2*Nn+j];
    fsh[tid][3]=xb[n]; fsh[tid][4]=xb[Nn+n]; fsh[tid][5]=xb[2*Nn+n];
  }
  __syncthreads();
  {
    float sc=sc1v[tid], sh=sh1v[tid];
    float w[6];
    #pragma unroll
    for (int i=0;i<6;++i) w[i]=W1f[i*64+tid];
    float mx = 0.f;
    #pragma unroll
    for (int r=0;r<Kk;++r){
      float y=0.f;
      #pragma unroll
      for (int i=0;i<6;++i) y = fmaf(fsh[r][i], w[i], y);
      float v = fmaxf(fmaf(y,sc,sh),0.f);
      h1[r][tid]=v;
      mx = fmaxf(mx,v);
    }
    cat[(size_t)bn*512 + tid] = f2b(mx);
  }
  __syncthreads();
  int q = tid >> 4, c0 = (tid & 15)*4;
  float acc[5][4]={};
  for (int i0=0;i0<64;i0+=4){
    float hv[5][4];
    #pragma unroll
    for (int l=0;l<5;++l){
      float4 t4 = *(const float4*)&h1[q*5+l][i0];
      hv[l][0]=t4.x; hv[l][1]=t4.y; hv[l][2]=t4.z; hv[l][3]=t4.w;
    }
    #pragma unroll
    for (int ii=0;ii<4;++ii){
      const float* wp = W2f + (i0+ii)*64 + c0;
      float w0=wp[0],w1=wp[1],w2=wp[2],w3=wp[3];
      #pragma unroll
      for (int l=0;l<5;++l){
        float hvv=hv[l][ii];
        acc[l][0]=fmaf(hvv,w0,acc[l][0]);
        acc[l][1]=fmaf(hvv,w1,acc[l][1]);
        acc[l][2]=fmaf(hvv,w2,acc[l][2]);
        acc[l][3]=fmaf(hvv,w3,acc[l][3]);
      }
    }
  }
  float sc[4],sh[4];
  #pragma unroll
  for (int cb=0;cb<4;++cb){ sc[cb]=sc2v[c0+cb]; sh[cb]=sh2v[c0+cb]; }
  float mx[4]={0,0,0,0};
  #pragma unroll
  for (int l=0;l<5;++l){
    unsigned short us[4];
    #pragma unroll
    for (int cb=0;cb<4;++cb){
      float v=fmaxf(fmaf(acc[l][cb],sc[cb],sh[cb]),0.f);
      mx[cb]=fmaxf(mx[cb],v);
      us[cb]=f2bu(v);
    }
    uint2 v2; v2.x = us[0]|((unsigned)us[1]<<16); v2.y=us[2]|((unsigned)us[3]<<16);
    *(uint2*)(H2 + ((size_t)bn*Kk + q*5+l)*64 + c0) = v2;
  }
  #pragma unroll
  for (int cb=0;cb<4;++cb) mm[q][c0+cb]=mx[cb];
  __syncthreads();
  {
    float M0 = fmaxf(fmaxf(mm[0][tid],mm[1][tid]),fmaxf(mm[2][tid],mm[3][tid]));
    cat[(size_t)bn*512 + 64 + tid] = f2b(M0);
  }
}

// ---------------- layer-4 stats: on-the-fly H3 -> Gram4(128x128) + colsum4 ----------------
__global__ __launch_bounds__(256) void stats4_kernel(const bf16* __restrict__ H2,
    const float* __restrict__ W3f, const float* __restrict__ sc3v, const float* __restrict__ sh3v,
    float* __restrict__ G4, float* __restrict__ sum4){
  __shared__ float W3s[64][128];
  __shared__ float h2s[16][64];
  __shared__ float h3s[16][128];
  __shared__ float scs[128], shs[128];
  int tid = threadIdx.x;
  for (int u=tid; u<64*128; u+=256) W3s[u>>7][u&127]=W3f[u];
  if (tid<128){ scs[tid]=sc3v[tid]; shs[tid]=sh3v[tid]; }
  __syncthreads();
  int rpc=(Mrows+gridDim.x-1)/gridDim.x;
  int r0=blockIdx.x*rpc, r1=min(Mrows,r0+rpc);
  int ty=tid>>4, tx=tid&15;
  int myc = tid & 127;
  float acc[8][8]={};
  float cs = 0.f;
  for (int rb=r0; rb<r1; rb+=16){
    for (int u=tid; u<1024; u+=256){
      int rr=u>>6, cc=u&63;
      float v=0.f;
      int row=rb+rr;
      if (row<r1) v=b2f(H2[(size_t)row*64+cc]);
      h2s[rr][cc]=v;
    }
    __syncthreads();
    #pragma unroll
    for (int k=0;k<8;++k){
      int rr=(tid>>7)+k*2;
      float y=0.f;
      for (int i=0;i<64;++i) y=fmaf(h2s[rr][i], W3s[i][myc], y);
      float v=fmaxf(fmaf(y,scs[myc],shs[myc]),0.f);
      if (rb+rr>=r1) v=0.f;
      h3s[rr][myc]=v;
      cs += v;
    }
    __syncthreads();
    for (int r=0;r<16;++r){
      float a[8], bq[8];
      #pragma unroll
      for (int u=0;u<8;++u){ a[u]=h3s[r][ty*8+u]; bq[u]=h3s[r][tx*8+u]; }
      #pragma unroll
      for (int u=0;u<8;++u)
        #pragma unroll
        for (int v=0;v<8;++v) acc[u][v]=fmaf(a[u],bq[v],acc[u][v]);
    }
    __syncthreads();
  }
  #pragma unroll
  for (int u=0;u<8;++u)
    #pragma unroll
    for (int v=0;v<8;++v)
      atomicAdd(&G4[(size_t)(ty*8+u)*128 + tx*8+v], acc[u][v]);
  atomicAdd(&sum4[myc], cs);
}

// ---------------- fused layers 3+4: H2 -> H3 -> x3, H3@W4 -> x4 ----------------
__global__ __launch_bounds__(128) void fl34_kernel(const bf16* __restrict__ H2,
    const float* __restrict__ W3f, const float* __restrict__ sc3v, const float* __restrict__ sh3v,
    const float* __restrict__ W4f, const float* __restrict__ sc4v, const float* __restrict__ sh4v,
    bf16* __restrict__ cat){
  __shared__ float h2s[Kk][64];
  __shared__ float h3s[Kk][128];
  __shared__ float w4s[16][256];
  __shared__ float mm[4][256];
  int bn = blockIdx.x, tid = threadIdx.x;
  const bf16* hp = H2 + (size_t)bn*Kk*64;
  for (int u=tid; u<Kk*64; u+=128) h2s[u>>6][u&63]=b2f(hp[u]);
  __syncthreads();
  {
    float y[Kk];
    #pragma unroll
    for (int r=0;r<Kk;++r) y[r]=0.f;
    for (int i=0;i<64;++i){
      float w = W3f[i*128 + tid];
      #pragma unroll
      for (int r=0;r<Kk;++r) y[r]=fmaf(h2s[r][i], w, y[r]);
    }
    float sc=sc3v[tid], sh=sh3v[tid];
    float mx=0.f;
    #pragma unroll
    for (int r=0;r<Kk;++r){
      float v=fmaxf(fmaf(y[r],sc,sh),0.f);
      h3s[r][tid]=v;
      mx=fmaxf(mx,v);
    }
    cat[(size_t)bn*512 + 128 + tid] = f2b(mx);
  }
  __syncthreads();
  int q = tid >> 5, cbase = tid & 31;
  float acc[5][8]={};
  for (int i0=0;i0<128;i0+=16){
    for (int u=tid;u<4096;u+=128) w4s[u>>8][u&255]=W4f[(size_t)(i0+(u>>8))*256+(u&255)];
    __syncthreads();
    for (int ii=0;ii<16;++ii){
      float w[8];
      #pragma unroll
      for (int cb=0;cb<8;++cb) w[cb]=w4s[ii][cbase + cb*32];
      float hv[5];
      #pragma unroll
      for (int l=0;l<5;++l) hv[l]=h3s[q*5+l][i0+ii];
      #pragma unroll
      for (int l=0;l<5;++l)
        #pragma unroll
        for (int cb=0;cb<8;++cb) acc[l][cb]=fmaf(hv[l],w[cb],acc[l][cb]);
    }
    __syncthreads();
  }
  float sc[8],sh[8];
  #pragma unroll
  for (int cb=0;cb<8;++cb){ sc[cb]=sc4v[cbase+cb*32]; sh[cb]=sh4v[cbase+cb*32]; }
  float mx[8];
  #pragma unroll
  for (int cb=0;cb<8;++cb) mx[cb]=0.f;
  #pragma unroll
  for (int l=0;l<5;++l)
    #pragma unroll
    for (int cb=0;cb<8;++cb){
      float v=fmaxf(fmaf(acc[l][cb],sc[cb],sh[cb]),0.f);
      mx[cb]=fmaxf(mx[cb],v);
    }
  #pragma unroll
  for (int cb=0;cb<8;++cb) mm[q][cbase+cb*32]=mx[cb];
  __syncthreads();
  for (int u=tid; u<256; u+=128){
    float M0 = fmaxf(fmaxf(mm[0][u],mm[1][u]),fmaxf(mm[2][u],mm[3][u]));
    cat[(size_t)bn*512 + 256 + u] = f2b(M0);
  }
}

// ---------------- layer 5: cat(bf16,512) @ W5, BN+ReLU, fp32 transposed store ----------------
__global__ __launch_bounds__(64) void l5_kernel(const bf16* __restrict__ cat,
                                                const float* __restrict__ Wf,
                                                const float* __restrict__ scale,
                                                const float* __restrict__ shift,
                                                float* __restrict__ out){
  __shared__ float cr[8][512];
  __shared__ float ob[8][512];
  int bn0 = blockIdx.x*8;
  for (int u=threadIdx.x; u<8*512; u+=64) cr[u>>9][u&511] = b2f(cat[(size_t)bn0*512 + u]);
  __syncthreads();
  int c0 = threadIdx.x*8;
  float acc[8][8];
  #pragma unroll
  for (int r=0;r<8;++r)
    #pragma unroll
    for (int cb=0;cb<8;++cb) acc[r][cb]=0.f;
  for (int i0=0;i0<512;i0+=4){
    float hva[8][4];
    #pragma unroll
    for (int r=0;r<8;++r){
      float4 t4 = *(const float4*)&cr[r][i0];
      hva[r][0]=t4.x; hva[r][1]=t4.y; hva[r][2]=t4.z; hva[r][3]=t4.w;
    }
    #pragma unroll
    for (int ii=0;ii<4;++ii){
      const float* wp = Wf + (size_t)(i0+ii)*512 + c0;
      float w[8];
      #pragma unroll
      for (int cb=0;cb<8;++cb) w[cb]=wp[cb];
      #pragma unroll
      for (int r=0;r<8;++r){
        float hv = hva[r][ii];
        #pragma unroll
        for (int cb=0;cb<8;++cb) acc[r][cb] = fmaf(hv, w[cb], acc[r][cb]);
      }
    }
  }
  float sc[8], sh[8];
  #pragma unroll
  for (int cb=0;cb<8;++cb){ sc[cb]=scale[c0+cb]; sh[cb]=shift[c0+cb]; }
  #pragma unroll
  for (int r=0;r<8;++r)
    #pragma unroll
    for (int cb=0;cb<8;++cb){
      float v = fmaxf(fmaf(acc[r][cb], sc[cb], sh[cb]), 0.f);
      ob[r][c0+cb] = v;
    }
  __syncthreads();
  int b = bn0 >> 12, n0 = bn0 & 4095;
  for (int u=threadIdx.x; u<512; u+=64){
    float4 v0 = make_float4(ob[0][u], ob[1][u], ob[2][u], ob[3][u]);
    float4 v1 = make_float4(ob[4][u], ob[5][u], ob[6][u], ob[7][u]);
    float* op = out + ((size_t)b*512 + u)*4096 + n0;
    *(float4*)(op)   = v0;
    *(float4*)(op+4) = v1;
  }
}

extern "C" void kernel_launch(void* const* d_in, const int* in_sizes, int n_in,
                              void* d_out, int out_size, void* d_ws, size_t ws_size,
                              hipStream_t stream){
  const float* x   = (const float*)d_in[0];
  const float* W1f = (const float*)d_in[1];
  const float* W2f = (const float*)d_in[2];
  const float* W3f = (const float*)d_in[3];
  const float* W4f = (const float*)d_in[4];
  const float* W5f = (const float*)d_in[5];
  const float* g1=(const float*)d_in[6],  *b1=(const float*)d_in[7];
  const float* g2=(const float*)d_in[8],  *b2=(const float*)d_in[9];
  const float* g3=(const float*)d_in[10], *b3=(const float*)d_in[11];
  const float* g4=(const float*)d_in[12], *b4=(const float*)d_in[13];
  const float* g5=(const float*)d_in[14], *b5=(const float*)d_in[15];
  float* out = (float*)d_out;

  char* w = (char*)d_ws;
  size_t off = 0;
  auto alloc = [&](size_t bytes)->void*{
    void* p = w + off;
    off = (off + bytes + 255) & ~(size_t)255;
    return p;
  };

  int*  idxb = (int*) alloc((size_t)BN*Kk*4);          // 2.6 MB
  bf16* H2   = (bf16*)alloc((size_t)Mrows*64*2);       // 84 MB
  bf16* catb = (bf16*)alloc((size_t)BN*512*2);         // 33.6 MB
  // KNN scratch aliases H2 (H2 first written by fl12, after knnB is done)
  float* pv  = (float*)H2;                             // 5.2 MB
  int*   pib = (int*)((char*)H2 + (size_t)BN*2*Kk*4);  // 5.2 MB

  size_t statsStart = off;
  float* partf=(float*)alloc(256*48*4);
  float* Gf=(float*)alloc(36*4);
  float* sumf=(float*)alloc(8*4);
  float* G2=(float*)alloc(4096*4);   float* sum2=(float*)alloc(64*4);
  float* G3=(float*)alloc(4096*4);   float* sum3=(float*)alloc(64*4);
  float* G4=(float*)alloc(16384*4);  float* sum4=(float*)alloc(128*4);
  float* G5=(float*)alloc(262144*4); float* sum5=(float*)alloc(512*4);
  float* P1=(float*)alloc(384*4);
  float* P2=(float*)alloc(4096*4);
  float* P3=(float*)alloc(8192*4);
  float* P4=(float*)alloc(32768*4);
  float* P5=(float*)alloc(262144*4);
  float* sc1=(float*)alloc(64*4);   float* sh1=(float*)alloc(64*4);
  float* sc2=(float*)alloc(64*4);   float* sh2=(float*)alloc(64*4);
  float* sc3=(float*)alloc(128*4);  float* sh3=(float*)alloc(128*4);
  float* sc4=(float*)alloc(256*4);  float* sh4=(float*)alloc(256*4);
  float* sc5=(float*)alloc(512*4);  float* sh5=(float*)alloc(512*4);
  size_t statsEnd = off;

  int statsFloats = (int)((statsEnd - statsStart)/4);
  zero_kernel<<<(statsFloats+255)/256,256,0,stream>>>((float*)(w+statsStart), statsFloats);

  knnA_kernel<<<256,256,0,stream>>>(x, pv, pib);
  knnB_kernel<<<BN/256,256,0,stream>>>(pv, pib, idxb);

  const float invM  = 1.0f/(float)Mrows;
  const float invM5 = 1.0f/(float)BN;

  // layer 1 stats
  gramf_kernel<<<256,256,0,stream>>>(x, idxb, partf);
  reducef_kernel<<<1,64,0,stream>>>(partf, Gf, sumf);
  kP_kernel<<<2,256,0,stream>>>(Gf, W1f, P1, 6, 64);
  kFinal_kernel<<<1,256,0,stream>>>(P1, sumf, W1f, g1, b1, sc1, sh1, 6, 64, invM);

  // layer 2 stats (on-the-fly H1)
  stats2_kernel<<<512,256,0,stream>>>(x, idxb, W1f, sc1, sh1, G2, sum2);
  kP_kernel<<<16,256,0,stream>>>(G2, W2f, P2, 64, 64);
  kFinal_kernel<<<1,256,0,stream>>>(P2, sum2, W2f, g2, b2, sc2, sh2, 64, 64, invM);

  // apply layers 1+2
  fl12_kernel<<<BN,64,0,stream>>>(x, idxb, W1f, sc1, sh1, W2f, sc2, sh2, H2, catb);

  // layer 3 stats from H2
  colsum_kernel<64,bf16><<<256,256,0,stream>>>(H2, Mrows, sum3);
  gram_kernel<64,bf16><<<512,256,0,stream>>>(H2, Mrows, G3);
  kP_kernel<<<32,256,0,stream>>>(G3, W3f, P3, 64, 128);
  kFinal_kernel<<<1,256,0,stream>>>(P3, sum3, W3f, g3, b3, sc3, sh3, 64, 128, invM);

  // layer 4 stats (on-the-fly H3)
  stats4_kernel<<<512,256,0,stream>>>(H2, W3f, sc3, sh3, G4, sum4);
  kP_kernel<<<128,256,0,stream>>>(G4, W4f, P4, 128, 256);
  kFinal_kernel<<<1,256,0,stream>>>(P4, sum4, W4f, g4, b4, sc4, sh4, 128, 256, invM);

  // apply layers 3+4
  fl34_kernel<<<BN,128,0,stream>>>(H2, W3f, sc3, sh3, W4f, sc4, sh4, catb);

  // layer 5
  colsum_kernel<512,bf16><<<256,256,0,stream>>>(catb, BN, sum5);
  gram_kernel<512,bf16><<<512,256,0,stream>>>(catb, BN, G5);
  kP_kernel<<<1024,256,0,stream>>>(G5, W5f, P5, 512, 512);
  kFinal_kernel<<<2,256,0,stream>>>(P5, sum5, W5f, g5, b5, sc5, sh5, 512, 512, invM5);
  l5_kernel<<<BN/8,64,0,stream>>>(catb, W5f, sc5, sh5, out);
}